// Round 1
// baseline (491.775 us; speedup 1.0000x reference)
//
#include <hip/hip_runtime.h>
#include <cmath>

#define HH 1024
#define BB 64

// d_out layout: c_new (B*H*H) | n_new (B*H) | m_new (B) | h (B*H)
#define C_ELEMS ((size_t)BB * HH * HH)

__device__ __forceinline__ float sigm(float v) { return 1.0f / (1.0f + expf(-v)); }

// ---------------- Kernel A: conv+silu -> qk ; gates i/f ; m_new ----------------
__global__ __launch_bounds__(256) void kA(
    const float* __restrict__ x, const float* __restrict__ m,
    const float* __restrict__ cw, const float* __restrict__ cb,
    const float* __restrict__ Wi, const float* __restrict__ bi,
    const float* __restrict__ Wf, const float* __restrict__ bf,
    float* __restrict__ qk, float* __restrict__ ig,
    float* __restrict__ fg, float* __restrict__ m_out)
{
    int b = blockIdx.x;
    int tid = threadIdx.x;
    const float* xb = x + (size_t)b * HH;
    float w0 = cw[0], w1 = cw[1], w2 = cw[2], w3 = cw[3], cbv = cb[0];
    float pi = 0.f, pf = 0.f;
    #pragma unroll
    for (int u = 0; u < 4; ++u) {
        int j = tid * 4 + u;
        // SAME pad for k=4: pad_low=1 -> taps x[j-1 .. j+2]
        float xm1 = (j - 1 >= 0) ? xb[j - 1] : 0.f;
        float x0  = xb[j];
        float xp1 = (j + 1 < HH) ? xb[j + 1] : 0.f;
        float xp2 = (j + 2 < HH) ? xb[j + 2] : 0.f;
        float s = cbv + xm1 * w0 + x0 * w1 + xp1 * w2 + xp2 * w3;
        qk[(size_t)b * HH + j] = s * sigm(s);   // silu
        pi += x0 * Wi[j];
        pf += x0 * Wf[j];
    }
    __shared__ float ri[256], rf[256];
    ri[tid] = pi; rf[tid] = pf;
    __syncthreads();
    for (int s = 128; s > 0; s >>= 1) {
        if (tid < s) { ri[tid] += ri[tid + s]; rf[tid] += rf[tid + s]; }
        __syncthreads();
    }
    if (tid == 0) {
        float it = ri[0] + bi[0];
        float ft = rf[0] + bf[0];
        float mo = m[b];
        float mn = fmaxf(ft + mo, it);
        m_out[b] = mn;
        ig[b] = expf(it - mn);
        fg[b] = expf(ft + mo - mn);
    }
}

// ---------------- Kernel B: split-K GEMMs (5 mats), partials to ws ----------------
// grid: (16 jtiles, 4 ksplits, 5 mats); block 256.
// tile: 64 b (all) x 64 j, over 256 i. Thread: 4b x 4j register block.
__global__ __launch_bounds__(256) void kB(
    const float* __restrict__ x, const float* __restrict__ qk,
    const float* __restrict__ Wo, const float* __restrict__ Wv,
    const float* __restrict__ Wk, const float* __restrict__ Wq,
    const float* __restrict__ Wsk, float* __restrict__ part)
{
    int jt = blockIdx.x, ks = blockIdx.y, mat = blockIdx.z;
    const float* W; const float* src;
    switch (mat) {
        case 0: W = Wo;  src = x;  break;
        case 1: W = Wv;  src = x;  break;
        case 2: W = Wk;  src = qk; break;
        case 3: W = Wq;  src = qk; break;
        default: W = Wsk; src = qk; break;
    }
    int j0 = jt * 64;
    int i_base = ks * 256;
    int tid = threadIdx.x;
    int jg = tid & 15;          // 16 j-groups (4 j each)
    int bg = tid >> 4;          // 16 b-groups (4 b each)
    int b0 = bg * 4;

    __shared__ float wlds[32 * 64];     // [ii][j]
    __shared__ float xlds[32 * 68];     // [ii][b], pad 68 for conflict-free b128

    float acc[4][4];
    #pragma unroll
    for (int a = 0; a < 4; ++a)
        #pragma unroll
        for (int d = 0; d < 4; ++d) acc[a][d] = 0.f;

    for (int ch = 0; ch < 8; ++ch) {
        int i0 = i_base + ch * 32;
        // stage W[i0..i0+31][j0..j0+63]
        {
            int ii = tid >> 4;
            int c4 = (tid & 15) * 4;
            float4 wa = *(const float4*)&W[(size_t)(i0 + ii) * HH + j0 + c4];
            float4 wb = *(const float4*)&W[(size_t)(i0 + ii + 16) * HH + j0 + c4];
            *(float4*)&wlds[ii * 64 + c4] = wa;
            *(float4*)&wlds[(ii + 16) * 64 + c4] = wb;
        }
        // stage x[b][i0..i0+31] transposed -> xlds[ii][b]
        {
            int b = tid >> 2;
            int ii0 = (tid & 3) * 8;
            float4 xa = *(const float4*)&src[(size_t)b * HH + i0 + ii0];
            float4 xb = *(const float4*)&src[(size_t)b * HH + i0 + ii0 + 4];
            xlds[(ii0 + 0) * 68 + b] = xa.x;
            xlds[(ii0 + 1) * 68 + b] = xa.y;
            xlds[(ii0 + 2) * 68 + b] = xa.z;
            xlds[(ii0 + 3) * 68 + b] = xa.w;
            xlds[(ii0 + 4) * 68 + b] = xb.x;
            xlds[(ii0 + 5) * 68 + b] = xb.y;
            xlds[(ii0 + 6) * 68 + b] = xb.z;
            xlds[(ii0 + 7) * 68 + b] = xb.w;
        }
        __syncthreads();
        #pragma unroll
        for (int ii = 0; ii < 32; ++ii) {
            float4 wv = *(const float4*)&wlds[ii * 64 + jg * 4];
            float4 xv = *(const float4*)&xlds[ii * 68 + b0];
            acc[0][0] += xv.x * wv.x; acc[0][1] += xv.x * wv.y;
            acc[0][2] += xv.x * wv.z; acc[0][3] += xv.x * wv.w;
            acc[1][0] += xv.y * wv.x; acc[1][1] += xv.y * wv.y;
            acc[1][2] += xv.y * wv.z; acc[1][3] += xv.y * wv.w;
            acc[2][0] += xv.z * wv.x; acc[2][1] += xv.z * wv.y;
            acc[2][2] += xv.z * wv.z; acc[2][3] += xv.z * wv.w;
            acc[3][0] += xv.w * wv.x; acc[3][1] += xv.w * wv.y;
            acc[3][2] += xv.w * wv.z; acc[3][3] += xv.w * wv.w;
        }
        __syncthreads();
    }
    float* p = part + (size_t)(mat * 4 + ks) * (BB * HH);
    #pragma unroll
    for (int a = 0; a < 4; ++a) {
        float4 v = make_float4(acc[a][0], acc[a][1], acc[a][2], acc[a][3]);
        *(float4*)&p[(size_t)(b0 + a) * HH + j0 + jg * 4] = v;
    }
}

// ---------------- Kernel C: reduce partials, bias/act, n_new, scaler ----------------
__global__ __launch_bounds__(256) void kC(
    const float* __restrict__ part, const float* __restrict__ n_in,
    const float* __restrict__ bo, const float* __restrict__ bv,
    const float* __restrict__ bk, const float* __restrict__ bq,
    const float* __restrict__ bsk,
    const float* __restrict__ ig, const float* __restrict__ fg,
    float* __restrict__ out_s, float* __restrict__ value_s,
    float* __restrict__ key_s, float* __restrict__ query_s,
    float* __restrict__ skip_s, float* __restrict__ scaler,
    float* __restrict__ n_out)
{
    int b = blockIdx.x;
    int tid = threadIdx.x;
    int j = tid * 4;
    size_t base = (size_t)b * HH + j;
    float4 s[5];
    #pragma unroll
    for (int mt = 0; mt < 5; ++mt) {
        float4 acc = make_float4(0.f, 0.f, 0.f, 0.f);
        #pragma unroll
        for (int ksp = 0; ksp < 4; ++ksp) {
            float4 v = *(const float4*)&part[(size_t)(mt * 4 + ksp) * (BB * HH) + base];
            acc.x += v.x; acc.y += v.y; acc.z += v.z; acc.w += v.w;
        }
        s[mt] = acc;
    }
    float4 b0v = *(const float4*)&bo[j];
    float4 b1v = *(const float4*)&bv[j];
    float4 b2v = *(const float4*)&bk[j];
    float4 b3v = *(const float4*)&bq[j];
    float4 b4v = *(const float4*)&bsk[j];

    float4 og = make_float4(sigm(s[0].x + b0v.x), sigm(s[0].y + b0v.y),
                            sigm(s[0].z + b0v.z), sigm(s[0].w + b0v.w));
    float4 vl = make_float4(s[1].x + b1v.x, s[1].y + b1v.y, s[1].z + b1v.z, s[1].w + b1v.w);
    const float rsH = 0.03125f; // 1/sqrt(1024)
    float4 ky = make_float4((s[2].x + b2v.x) * rsH, (s[2].y + b2v.y) * rsH,
                            (s[2].z + b2v.z) * rsH, (s[2].w + b2v.w) * rsH);
    float4 qu = make_float4(s[3].x + b3v.x, s[3].y + b3v.y, s[3].z + b3v.z, s[3].w + b3v.w);
    float4 sk = make_float4(s[4].x + b4v.x, s[4].y + b4v.y, s[4].z + b4v.z, s[4].w + b4v.w);

    *(float4*)&out_s[base]   = og;
    *(float4*)&value_s[base] = vl;
    *(float4*)&key_s[base]   = ky;
    *(float4*)&query_s[base] = qu;
    *(float4*)&skip_s[base]  = sk;

    float igv = ig[b], fgv = fg[b];
    float4 nv = *(const float4*)&n_in[base];
    float4 nn = make_float4(fgv * nv.x + igv * ky.x, fgv * nv.y + igv * ky.y,
                            fgv * nv.z + igv * ky.z, fgv * nv.w + igv * ky.w);
    *(float4*)&n_out[base] = nn;

    float d = nn.x * qu.x + nn.y * qu.y + nn.z * qu.z + nn.w * qu.w;
    __shared__ float red[256];
    red[tid] = d;
    __syncthreads();
    for (int s2 = 128; s2 > 0; s2 >>= 1) {
        if (tid < s2) red[tid] += red[tid + s2];
        __syncthreads();
    }
    if (tid == 0) scaler[b] = 1.0f / fmaxf(fabsf(red[0]), 1.0f);
}

// ---------------- Kernel D: stream c -> c_new, fused row-dot -> h ----------------
// wave per row (b,i); 4 waves per block; grid 65536/4 = 16384
__global__ __launch_bounds__(256) void kD(
    const float* __restrict__ c,
    const float* __restrict__ key_s, const float* __restrict__ query_s,
    const float* __restrict__ value_s, const float* __restrict__ out_s,
    const float* __restrict__ skip_s, const float* __restrict__ ig,
    const float* __restrict__ fg, const float* __restrict__ scaler,
    float* __restrict__ c_out, float* __restrict__ h_out)
{
    int wid = threadIdx.x >> 6;
    int lane = threadIdx.x & 63;
    int r = blockIdx.x * 4 + wid;      // r = b*H + i
    int b = r >> 10;
    float fgv = fg[b];
    float iv = ig[b] * value_s[r];
    const float* crow = c + ((size_t)r << 10);
    float* orow = c_out + ((size_t)r << 10);
    const float* keyb = key_s + (size_t)b * HH;
    const float* qb = query_s + (size_t)b * HH;
    float dot = 0.f;
    #pragma unroll
    for (int kk = 0; kk < 4; ++kk) {
        int k = kk * 256 + lane * 4;
        float4 c4 = *(const float4*)&crow[k];
        float4 k4 = *(const float4*)&keyb[k];
        float4 q4 = *(const float4*)&qb[k];
        float4 cn;
        cn.x = fgv * c4.x + iv * k4.x;
        cn.y = fgv * c4.y + iv * k4.y;
        cn.z = fgv * c4.z + iv * k4.z;
        cn.w = fgv * c4.w + iv * k4.w;
        *(float4*)&orow[k] = cn;
        dot += cn.x * q4.x + cn.y * q4.y + cn.z * q4.z + cn.w * q4.w;
    }
    #pragma unroll
    for (int d = 32; d > 0; d >>= 1) dot += __shfl_down(dot, d, 64);
    if (lane == 0)
        h_out[r] = out_s[r] * dot * scaler[b] + skip_s[r];
}

extern "C" void kernel_launch(void* const* d_in, const int* in_sizes, int n_in,
                              void* d_out, int out_size, void* d_ws, size_t ws_size,
                              hipStream_t stream)
{
    const float* c   = (const float*)d_in[0];
    const float* n   = (const float*)d_in[1];
    const float* m   = (const float*)d_in[2];
    const float* x   = (const float*)d_in[3];
    const float* Wq  = (const float*)d_in[4];
    const float* bq  = (const float*)d_in[5];
    const float* Wk  = (const float*)d_in[6];
    const float* bk  = (const float*)d_in[7];
    const float* Wv  = (const float*)d_in[8];
    const float* bv  = (const float*)d_in[9];
    const float* cw  = (const float*)d_in[10];
    const float* cb  = (const float*)d_in[11];
    const float* Wi  = (const float*)d_in[12];
    const float* bi  = (const float*)d_in[13];
    const float* Wf  = (const float*)d_in[14];
    const float* bf  = (const float*)d_in[15];
    const float* Wo  = (const float*)d_in[16];
    const float* bo  = (const float*)d_in[17];
    const float* Wsk = (const float*)d_in[18];
    const float* bsk = (const float*)d_in[19];

    float* out = (float*)d_out;
    float* ws  = (float*)d_ws;

    const int BH = BB * HH; // 65536
    // ws layout (floats)
    float* qk      = ws;                    // BH
    float* ig      = ws + BH;               // 64
    float* fg      = ig + BB;               // 64
    float* scaler  = fg + BB;               // 64
    float* fin     = scaler + BB;
    float* out_s   = fin + 0 * BH;
    float* value_s = fin + 1 * BH;
    float* key_s   = fin + 2 * BH;
    float* query_s = fin + 3 * BH;
    float* skip_s  = fin + 4 * BH;
    float* part    = fin + 5 * BH;          // 20 * BH

    float* c_out = out;
    float* n_out = out + C_ELEMS;
    float* m_out = out + C_ELEMS + BH;
    float* h_out = m_out + BB;

    kA<<<BB, 256, 0, stream>>>(x, m, cw, cb, Wi, bi, Wf, bf, qk, ig, fg, m_out);
    dim3 gB(16, 4, 5);
    kB<<<gB, 256, 0, stream>>>(x, qk, Wo, Wv, Wk, Wq, Wsk, part);
    kC<<<BB, 256, 0, stream>>>(part, n, bo, bv, bk, bq, bsk, ig, fg,
                               out_s, value_s, key_s, query_s, skip_s, scaler, n_out);
    kD<<<BH / 4, 256, 0, stream>>>(c, key_s, query_s, value_s, out_s, skip_s,
                                   ig, fg, scaler, c_out, h_out);
}

// Round 2
// 481.142 us; speedup vs baseline: 1.0221x; 1.0221x over previous
//
#include <hip/hip_runtime.h>
#include <cmath>

#define HH 1024
#define BB 64

// d_out layout: c_new (B*H*H) | n_new (B*H) | m_new (B) | h (B*H)
#define C_ELEMS ((size_t)BB * HH * HH)

typedef float f4 __attribute__((ext_vector_type(4)));

__device__ __forceinline__ float sigm(float v) { return 1.0f / (1.0f + expf(-v)); }

// ---------------- Kernel A: conv+silu -> qk ; gates i/f ; m_new ----------------
__global__ __launch_bounds__(256) void kA(
    const float* __restrict__ x, const float* __restrict__ m,
    const float* __restrict__ cw, const float* __restrict__ cb,
    const float* __restrict__ Wi, const float* __restrict__ bi,
    const float* __restrict__ Wf, const float* __restrict__ bf,
    float* __restrict__ qk, float* __restrict__ ig,
    float* __restrict__ fg, float* __restrict__ m_out)
{
    int b = blockIdx.x;
    int tid = threadIdx.x;
    const float* xb = x + (size_t)b * HH;
    float w0 = cw[0], w1 = cw[1], w2 = cw[2], w3 = cw[3], cbv = cb[0];
    int j4 = tid * 4;
    float4 xv = *(const float4*)&xb[j4];
    float xm1 = (tid > 0) ? xb[j4 - 1] : 0.f;
    float xp4 = (tid < 255) ? xb[j4 + 4] : 0.f;
    float xp5 = (tid < 255) ? xb[j4 + 5] : 0.f;
    // SAME pad k=4: pad_lo=1 -> out[j] = w0*x[j-1]+w1*x[j]+w2*x[j+1]+w3*x[j+2]
    float s0 = cbv + w0 * xm1  + w1 * xv.x + w2 * xv.y + w3 * xv.z;
    float s1 = cbv + w0 * xv.x + w1 * xv.y + w2 * xv.z + w3 * xv.w;
    float s2 = cbv + w0 * xv.y + w1 * xv.z + w2 * xv.w + w3 * xp4;
    float s3 = cbv + w0 * xv.z + w1 * xv.w + w2 * xp4  + w3 * xp5;
    float4 q;
    q.x = s0 * sigm(s0); q.y = s1 * sigm(s1);
    q.z = s2 * sigm(s2); q.w = s3 * sigm(s3);
    *(float4*)&qk[(size_t)b * HH + j4] = q;

    float4 wi4 = *(const float4*)&Wi[j4];
    float4 wf4 = *(const float4*)&Wf[j4];
    float pi = xv.x * wi4.x + xv.y * wi4.y + xv.z * wi4.z + xv.w * wi4.w;
    float pf = xv.x * wf4.x + xv.y * wf4.y + xv.z * wf4.z + xv.w * wf4.w;

    __shared__ float ri[256], rf[256];
    ri[tid] = pi; rf[tid] = pf;
    __syncthreads();
    for (int s = 128; s > 0; s >>= 1) {
        if (tid < s) { ri[tid] += ri[tid + s]; rf[tid] += rf[tid + s]; }
        __syncthreads();
    }
    if (tid == 0) {
        float it = ri[0] + bi[0];
        float ft = rf[0] + bf[0];
        float mo = m[b];
        float mn = fmaxf(ft + mo, it);
        m_out[b] = mn;
        ig[b] = expf(it - mn);
        fg[b] = expf(ft + mo - mn);
    }
}

// ---------------- Kernel B: split-K GEMMs (5 mats), partials to ws ----------------
// grid: (16 jtiles, 8 ksplits, 5 mats) = 640 blocks; block 256.
// tile: 64 b x 64 j, over 128 i. Thread: 4b x 4j register block.
__global__ __launch_bounds__(256) void kB(
    const float* __restrict__ x, const float* __restrict__ qk,
    const float* __restrict__ Wo, const float* __restrict__ Wv,
    const float* __restrict__ Wk, const float* __restrict__ Wq,
    const float* __restrict__ Wsk, float* __restrict__ part)
{
    int jt = blockIdx.x, ks = blockIdx.y, mat = blockIdx.z;
    const float* W; const float* src;
    switch (mat) {
        case 0: W = Wo;  src = x;  break;
        case 1: W = Wv;  src = x;  break;
        case 2: W = Wk;  src = qk; break;
        case 3: W = Wq;  src = qk; break;
        default: W = Wsk; src = qk; break;
    }
    int j0 = jt * 64;
    int i_base = ks * 128;
    int tid = threadIdx.x;
    int jg = tid & 15;          // 16 j-groups (4 j each)
    int bg = tid >> 4;          // 16 b-groups (4 b each)
    int b0 = bg * 4;

    __shared__ float wlds[32 * 64];     // [ii][j]
    __shared__ float xlds[32 * 68];     // [ii][b], pad 68 to break conflicts

    float acc[4][4];
    #pragma unroll
    for (int a = 0; a < 4; ++a)
        #pragma unroll
        for (int d = 0; d < 4; ++d) acc[a][d] = 0.f;

    for (int ch = 0; ch < 4; ++ch) {
        int i0 = i_base + ch * 32;
        // stage W[i0..i0+31][j0..j0+63]
        {
            int ii = tid >> 4;
            int c4 = (tid & 15) * 4;
            float4 wa = *(const float4*)&W[(size_t)(i0 + ii) * HH + j0 + c4];
            float4 wb = *(const float4*)&W[(size_t)(i0 + ii + 16) * HH + j0 + c4];
            *(float4*)&wlds[ii * 64 + c4] = wa;
            *(float4*)&wlds[(ii + 16) * 64 + c4] = wb;
        }
        // stage src[b][i0..i0+31] transposed -> xlds[ii][b]
        {
            int b = tid >> 2;
            int ii0 = (tid & 3) * 8;
            float4 xa = *(const float4*)&src[(size_t)b * HH + i0 + ii0];
            float4 xb = *(const float4*)&src[(size_t)b * HH + i0 + ii0 + 4];
            xlds[(ii0 + 0) * 68 + b] = xa.x;
            xlds[(ii0 + 1) * 68 + b] = xa.y;
            xlds[(ii0 + 2) * 68 + b] = xa.z;
            xlds[(ii0 + 3) * 68 + b] = xa.w;
            xlds[(ii0 + 4) * 68 + b] = xb.x;
            xlds[(ii0 + 5) * 68 + b] = xb.y;
            xlds[(ii0 + 6) * 68 + b] = xb.z;
            xlds[(ii0 + 7) * 68 + b] = xb.w;
        }
        __syncthreads();
        #pragma unroll
        for (int ii = 0; ii < 32; ++ii) {
            float4 wv = *(const float4*)&wlds[ii * 64 + jg * 4];
            float4 xv = *(const float4*)&xlds[ii * 68 + b0];
            acc[0][0] += xv.x * wv.x; acc[0][1] += xv.x * wv.y;
            acc[0][2] += xv.x * wv.z; acc[0][3] += xv.x * wv.w;
            acc[1][0] += xv.y * wv.x; acc[1][1] += xv.y * wv.y;
            acc[1][2] += xv.y * wv.z; acc[1][3] += xv.y * wv.w;
            acc[2][0] += xv.z * wv.x; acc[2][1] += xv.z * wv.y;
            acc[2][2] += xv.z * wv.z; acc[2][3] += xv.z * wv.w;
            acc[3][0] += xv.w * wv.x; acc[3][1] += xv.w * wv.y;
            acc[3][2] += xv.w * wv.z; acc[3][3] += xv.w * wv.w;
        }
        __syncthreads();
    }
    float* p = part + (size_t)(mat * 8 + ks) * (BB * HH);
    #pragma unroll
    for (int a = 0; a < 4; ++a) {
        float4 v = make_float4(acc[a][0], acc[a][1], acc[a][2], acc[a][3]);
        *(float4*)&p[(size_t)(b0 + a) * HH + j0 + jg * 4] = v;
    }
}

// ---------------- Kernel C: reduce partials, bias/act, n_new, scaler ----------------
__global__ __launch_bounds__(256) void kC(
    const float* __restrict__ part, const float* __restrict__ n_in,
    const float* __restrict__ bo, const float* __restrict__ bv,
    const float* __restrict__ bk, const float* __restrict__ bq,
    const float* __restrict__ bsk,
    const float* __restrict__ ig, const float* __restrict__ fg,
    float* __restrict__ out_s, float* __restrict__ value_s,
    float* __restrict__ key_s, float* __restrict__ query_s,
    float* __restrict__ skip_s, float* __restrict__ scaler,
    float* __restrict__ n_out)
{
    int b = blockIdx.x;
    int tid = threadIdx.x;
    int j = tid * 4;
    size_t base = (size_t)b * HH + j;
    float4 s[5];
    #pragma unroll
    for (int mt = 0; mt < 5; ++mt) {
        float4 acc = make_float4(0.f, 0.f, 0.f, 0.f);
        #pragma unroll
        for (int ksp = 0; ksp < 8; ++ksp) {
            float4 v = *(const float4*)&part[(size_t)(mt * 8 + ksp) * (BB * HH) + base];
            acc.x += v.x; acc.y += v.y; acc.z += v.z; acc.w += v.w;
        }
        s[mt] = acc;
    }
    float4 b0v = *(const float4*)&bo[j];
    float4 b1v = *(const float4*)&bv[j];
    float4 b2v = *(const float4*)&bk[j];
    float4 b3v = *(const float4*)&bq[j];
    float4 b4v = *(const float4*)&bsk[j];

    float4 og = make_float4(sigm(s[0].x + b0v.x), sigm(s[0].y + b0v.y),
                            sigm(s[0].z + b0v.z), sigm(s[0].w + b0v.w));
    float4 vl = make_float4(s[1].x + b1v.x, s[1].y + b1v.y, s[1].z + b1v.z, s[1].w + b1v.w);
    const float rsH = 0.03125f; // 1/sqrt(1024)
    float4 ky = make_float4((s[2].x + b2v.x) * rsH, (s[2].y + b2v.y) * rsH,
                            (s[2].z + b2v.z) * rsH, (s[2].w + b2v.w) * rsH);
    float4 qu = make_float4(s[3].x + b3v.x, s[3].y + b3v.y, s[3].z + b3v.z, s[3].w + b3v.w);
    float4 sk = make_float4(s[4].x + b4v.x, s[4].y + b4v.y, s[4].z + b4v.z, s[4].w + b4v.w);

    *(float4*)&out_s[base]   = og;
    *(float4*)&value_s[base] = vl;
    *(float4*)&key_s[base]   = ky;
    *(float4*)&query_s[base] = qu;
    *(float4*)&skip_s[base]  = sk;

    float igv = ig[b], fgv = fg[b];
    float4 nv = *(const float4*)&n_in[base];
    float4 nn = make_float4(fgv * nv.x + igv * ky.x, fgv * nv.y + igv * ky.y,
                            fgv * nv.z + igv * ky.z, fgv * nv.w + igv * ky.w);
    *(float4*)&n_out[base] = nn;

    float d = nn.x * qu.x + nn.y * qu.y + nn.z * qu.z + nn.w * qu.w;
    __shared__ float red[256];
    red[tid] = d;
    __syncthreads();
    for (int s2 = 128; s2 > 0; s2 >>= 1) {
        if (tid < s2) red[tid] += red[tid + s2];
        __syncthreads();
    }
    if (tid == 0) scaler[b] = 1.0f / fmaxf(fabsf(red[0]), 1.0f);
}

// ---------------- Kernel D: stream c -> c_new (non-temporal), fused row-dot -> h ----------------
// wave per row (b,i); 4 waves per block; grid 65536/4 = 16384
__global__ __launch_bounds__(256) void kD(
    const float* __restrict__ c,
    const float* __restrict__ key_s, const float* __restrict__ query_s,
    const float* __restrict__ value_s, const float* __restrict__ out_s,
    const float* __restrict__ skip_s, const float* __restrict__ ig,
    const float* __restrict__ fg, const float* __restrict__ scaler,
    float* __restrict__ c_out, float* __restrict__ h_out)
{
    int wid = threadIdx.x >> 6;
    int lane = threadIdx.x & 63;
    int r = blockIdx.x * 4 + wid;      // r = b*H + i
    int b = r >> 10;
    float fgv = fg[b];
    float iv = ig[b] * value_s[r];
    const f4* crow = (const f4*)(c + ((size_t)r << 10));
    f4* orow = (f4*)(c_out + ((size_t)r << 10));
    const float* keyb = key_s + (size_t)b * HH;
    const float* qb = query_s + (size_t)b * HH;
    float dot = 0.f;
    #pragma unroll
    for (int kk = 0; kk < 4; ++kk) {
        int k4 = kk * 64 + lane;           // float4 index within row
        f4 c4 = __builtin_nontemporal_load(&crow[k4]);   // streaming: bypass cache reuse
        float4 kx = *(const float4*)&keyb[k4 * 4];       // hot in L2 (reused per b)
        float4 q4 = *(const float4*)&qb[k4 * 4];
        f4 cn;
        cn.x = fgv * c4.x + iv * kx.x;
        cn.y = fgv * c4.y + iv * kx.y;
        cn.z = fgv * c4.z + iv * kx.z;
        cn.w = fgv * c4.w + iv * kx.w;
        __builtin_nontemporal_store(cn, &orow[k4]);      // streaming store: no write-allocate
        dot += cn.x * q4.x + cn.y * q4.y + cn.z * q4.z + cn.w * q4.w;
    }
    #pragma unroll
    for (int d = 32; d > 0; d >>= 1) dot += __shfl_down(dot, d, 64);
    if (lane == 0)
        h_out[r] = out_s[r] * dot * scaler[b] + skip_s[r];
}

extern "C" void kernel_launch(void* const* d_in, const int* in_sizes, int n_in,
                              void* d_out, int out_size, void* d_ws, size_t ws_size,
                              hipStream_t stream)
{
    const float* c   = (const float*)d_in[0];
    const float* n   = (const float*)d_in[1];
    const float* m   = (const float*)d_in[2];
    const float* x   = (const float*)d_in[3];
    const float* Wq  = (const float*)d_in[4];
    const float* bq  = (const float*)d_in[5];
    const float* Wk  = (const float*)d_in[6];
    const float* bk  = (const float*)d_in[7];
    const float* Wv  = (const float*)d_in[8];
    const float* bv  = (const float*)d_in[9];
    const float* cw  = (const float*)d_in[10];
    const float* cb  = (const float*)d_in[11];
    const float* Wi  = (const float*)d_in[12];
    const float* bi  = (const float*)d_in[13];
    const float* Wf  = (const float*)d_in[14];
    const float* bf  = (const float*)d_in[15];
    const float* Wo  = (const float*)d_in[16];
    const float* bo  = (const float*)d_in[17];
    const float* Wsk = (const float*)d_in[18];
    const float* bsk = (const float*)d_in[19];

    float* out = (float*)d_out;
    float* ws  = (float*)d_ws;

    const int BH = BB * HH; // 65536
    // ws layout (floats)
    float* qk      = ws;                    // BH
    float* ig      = ws + BH;               // 64
    float* fg      = ig + BB;               // 64
    float* scaler  = fg + BB;               // 64
    float* fin     = scaler + BB;
    float* out_s   = fin + 0 * BH;
    float* value_s = fin + 1 * BH;
    float* key_s   = fin + 2 * BH;
    float* query_s = fin + 3 * BH;
    float* skip_s  = fin + 4 * BH;
    float* part    = fin + 5 * BH;          // 40 * BH

    float* c_out = out;
    float* n_out = out + C_ELEMS;
    float* m_out = out + C_ELEMS + BH;
    float* h_out = m_out + BB;

    kA<<<BB, 256, 0, stream>>>(x, m, cw, cb, Wi, bi, Wf, bf, qk, ig, fg, m_out);
    dim3 gB(16, 8, 5);
    kB<<<gB, 256, 0, stream>>>(x, qk, Wo, Wv, Wk, Wq, Wsk, part);
    kC<<<BB, 256, 0, stream>>>(part, n, bo, bv, bk, bq, bsk, ig, fg,
                               out_s, value_s, key_s, query_s, skip_s, scaler, n_out);
    kD<<<BH / 4, 256, 0, stream>>>(c, key_s, query_s, value_s, out_s, skip_s,
                                   ig, fg, scaler, c_out, h_out);
}